// Round 1
// 186.046 us; speedup vs baseline: 1.0084x; 1.0084x over previous
//
#include <hip/hip_runtime.h>

// Luong attention: B=4, Q=K=2048, D=1024, fp32 in/out.
// R8: gemm_s rewritten as 256x256-tile BK=64 8-wave 8-phase counted-vmcnt
// kernel (T2 swizzle + T3/T4 schedule + T5 setprio). gemm_o / prep_all /
// gemm_pv / tier-3 unchanged from R7.

#define SQ 2048
#define SK 2048
#define DD 1024
#define NB 4

typedef _Float16 f16;
typedef _Float16 f16x8 __attribute__((ext_vector_type(8)));
typedef _Float16 f16x4 __attribute__((ext_vector_type(4)));
typedef short s16x8 __attribute__((ext_vector_type(8)));
typedef short s16x4 __attribute__((ext_vector_type(4)));
typedef float f32x4 __attribute__((ext_vector_type(4)));

#define L2E 1.44269504f
#define SHIFT_L2E 184.664965f   // 128 * log2(e)

__device__ __forceinline__ unsigned short bf16rne(float x){
  unsigned u = __float_as_uint(x);
  return (unsigned short)((u + 0x7FFFu + ((u >> 16) & 1u)) >> 16);
}
__device__ __forceinline__ void async16(const void* g, void* l){
  __builtin_amdgcn_global_load_lds((const __attribute__((address_space(1))) void*)g,
                                   (__attribute__((address_space(3))) void*)l,
                                   16, 0, 0);
}

// =================== prepass: Q16 + V16 + tiled VTt, one kernel ===================
// VTt layout: [b][dt:8][kt:32][d:128][ch:8 @ pos ch^(d&7)][8 bf16] -> 16KB tiles.

__global__ __launch_bounds__(256)
void prep_all(const float* __restrict__ Qg, const float* __restrict__ Vg,
              f16* __restrict__ Q16, f16* __restrict__ V16,
              unsigned short* __restrict__ VTt)
{
  __shared__ float T[64][65];
  const int bid = blockIdx.x;
  const int tid = threadIdx.x;

  if (bid >= 2048){
    // ---- Q part: f32 -> f16, 8 elems/thread ----
    size_t i = (size_t)(bid - 2048) * 256 + tid;
    const float4* p = (const float4*)Qg + i*2;
    float4 a = p[0], b = p[1];
    f16x8 h = { (f16)a.x,(f16)a.y,(f16)a.z,(f16)a.w,
                (f16)b.x,(f16)b.y,(f16)b.z,(f16)b.w };
    *(f16x8*)(Q16 + i*8) = h;
    return;
  }

  // ---- V part: 64j x 64d tile -> V16 (row-major f16) + VTt (tiled bf16) ----
  const int b  = bid >> 9;
  const int jt = (bid >> 4) & 31;
  const int dt16 = bid & 15;
  const int j0 = jt*64, d0 = dt16*64;
  const int c4 = (tid & 15) * 4;
  const int jl = tid >> 4;

  const float* src = Vg + ((size_t)b*SK + j0)*DD + d0;
  #pragma unroll
  for (int it = 0; it < 4; ++it){
    int j = jl + it*16;
    float4 x = *(const float4*)(src + (size_t)j*DD + c4);
    f16x4 h = {(f16)x.x,(f16)x.y,(f16)x.z,(f16)x.w};
    *(f16x4*)(V16 + ((size_t)b*SK + j0 + j)*DD + d0 + c4) = h;
    T[j][c4+0]=x.x; T[j][c4+1]=x.y; T[j][c4+2]=x.z; T[j][c4+3]=x.w;
  }
  __syncthreads();

  const int dl = tid >> 2;            // 0..63
  const int js = (tid & 3) * 16;      // 16 k's = chunks ch0, ch0+1 of BK=64 tile jt
  unsigned short tmp[16];
  #pragma unroll
  for (int i = 0; i < 16; ++i)
    tmp[i] = bf16rne(T[js+i][dl]);

  const int d    = d0 + dl;
  const int dt   = d >> 7;
  const int dloc = d & 127;
  const int ch0  = js >> 3;           // 0,2,4,6
  unsigned short* row = VTt + ((size_t)((b*8 + dt)*32 + jt)*128 + dloc)*64;
  *(uint4*)(row + (( ch0   ^ (dloc & 7)) * 8)) = *(uint4*)&tmp[0];
  *(uint4*)(row + (((ch0+1) ^ (dloc & 7)) * 8)) = *(uint4*)&tmp[8];
}

// tier-2 prepass
__global__ __launch_bounds__(256) void cvt_f16(const float* __restrict__ src,
                                               f16* __restrict__ dst)
{
  size_t i = (size_t)blockIdx.x * 256 + threadIdx.x;
  const float4* p = (const float4*)src + i*2;
  float4 a = p[0], b = p[1];
  f16x8 h = { (f16)a.x,(f16)a.y,(f16)a.z,(f16)a.w,
              (f16)b.x,(f16)b.y,(f16)b.z,(f16)b.w };
  *(f16x8*)(dst + i*8) = h;
}

// =================== Kernel A: P = exp(Q*V^T - 128), 256^2 8-phase ===================
// Tile 256x256, BK=64, 8 waves (2M x 4N), per-wave 128x64 output.
// LDS 128KB: buf b at b*65536: A-u0(16K) A-u1(16K) B-u0(16K) B-u1(16K).
//   A-u0 = tile rows {0-63,128-191}   (MFMA row-half mqh=0 of both wave rows)
//   A-u1 = tile rows {64-127,192-255}
//   B-u0 = V rows {0-31,64-95,128-159,192-223}   (n-quadrant nqh=0 per wave col)
//   B-u1 = V rows {32-63,96-127,160-191,224-255}
// Within a unit: 128 rows x 128B, chunk ch of row r stored at pos ch^(r&7)
// (swizzle applied on the GLOBAL source address; LDS dest linear).
// Phase schedule per iter (K-steps 2it,2it+1), stages & waits verified race-free:
//   P1 (0,0)b0: stage A1(b1,k1); P2 (0,1)b0: B1(b1,k1); P3 (1,0)b0: A0(b0,k2);
//   P4 (1,1)b0: B0(b0,k2); P5 (0,0)b1: A1(b0,k2); P6 (0,1)b1: B1(b0,k2);
//   P7 (1,0)b1: A0(b1,k3); P8 (1,1)b1: B0(b1,k3).
// End-of-phase vmcnt: P1:6 P2:10 P3:10 P4:8 P5:6 P6:10 P7:10 P8:8.
// P layout (unchanged): [b*16+qt][jc:32][q:128][chunk:8 @ pos ch^(q&7)][8 bf16]

__global__ __launch_bounds__(512, 2)
void gemm_s(const f16* __restrict__ Q16, const f16* __restrict__ V16,
            unsigned short* __restrict__ Pt)
{
  extern __shared__ char smem[];                 // 131072 B

  const int tid  = threadIdx.x;
  const int w    = tid >> 6, lane = tid & 63;
  const int l16  = lane & 15, quad = lane >> 4;
  const int wr   = w >> 2;            // 0..1  M half
  const int wc   = w & 3;             // 0..3  N quarter

  // XCD supertile: b -> XCD pair, 8qt x 4jt per XCD
  const int x = blockIdx.x & 7;
  const int s = blockIdx.x >> 3;      // 0..31
  const int b   = x >> 1;
  const int h   = x & 1;
  const int qt2 = s >> 2;             // 0..7 (256-row Q tile)
  const int jt2 = h*4 + (s & 3);      // 0..7 (256-row V tile)

  const char* Abase = (const char*)(Q16 + ((size_t)b*SQ + qt2*256)*DD);
  const char* Bbase = (const char*)(V16 + ((size_t)b*SK + jt2*256)*DD);

  // per-lane staging source offsets (issue i covers unit element i*512+tid)
  int aoff0, aoff1, boff0, boff1;
  {
    int rp0 = tid >> 3;                       // row-in-unit, issue 0
    int c0  = (tid & 7) ^ (rp0 & 7);          // source chunk (pre-swizzle)
    aoff0 = (((rp0 >> 6)*128) + (rp0 & 63))*2048 + c0*16;
    boff0 = (((rp0 >> 5)*64 ) + (rp0 & 31))*2048 + c0*16;
    int rp1 = 64 + rp0;                       // issue 1
    int c1  = (tid & 7) ^ (rp1 & 7);
    aoff1 = (((rp1 >> 6)*128) + (rp1 & 63))*2048 + c1*16;
    boff1 = (((rp1 >> 5)*64 ) + (rp1 & 31))*2048 + c1*16;
  }

  const int aRdOff = (wr*64 + l16)*128;
  const int bRdOff = (wc*32 + l16)*128;
  const int pos0   = (quad ^ (l16 & 7)) * 16; // kk=0 chunk pos; kk=1 = pos0^64

  f32x4 o[8][4];
  #pragma unroll
  for (int mi = 0; mi < 8; ++mi)
    #pragma unroll
    for (int ni = 0; ni < 4; ++ni)
      o[mi][ni] = (f32x4){0.f,0.f,0.f,0.f};

  f16x8 af[4][2], bfa[2][2], bfb[2][2];

  auto STAGEA = [&](int BB, int U, int KS){
    char* lb = smem + BB*65536 + U*16384 + w*1024;
    const char* g = Abase + U*131072 + KS*128;
    async16(g + aoff0, lb);
    async16(g + aoff1, lb + 8192);
  };
  auto STAGEB = [&](int BB, int U, int KS){
    char* lb = smem + BB*65536 + 32768 + U*16384 + w*1024;
    const char* g = Bbase + U*65536 + KS*128;
    async16(g + boff0, lb);
    async16(g + boff1, lb + 8192);
  };
  auto LOADA = [&](int BB, int MQH){
    const char* ab = smem + BB*65536 + MQH*16384 + aRdOff;
    #pragma unroll
    for (int m2 = 0; m2 < 4; ++m2){
      af[m2][0] = *(const f16x8*)(ab + m2*2048 + pos0);
      af[m2][1] = *(const f16x8*)(ab + m2*2048 + (pos0 ^ 64));
    }
  };
  auto LOADB = [&](int BB, int NQH, f16x8 (*bf)[2]){
    const char* bb = smem + BB*65536 + 32768 + NQH*16384 + bRdOff;
    #pragma unroll
    for (int n2 = 0; n2 < 2; ++n2){
      bf[n2][0] = *(const f16x8*)(bb + n2*2048 + pos0);
      bf[n2][1] = *(const f16x8*)(bb + n2*2048 + (pos0 ^ 64));
    }
  };
  auto QUAD = [&](int MQH, int NQH, f16x8 (*bf)[2]){
    __builtin_amdgcn_s_setprio(1);
    #pragma unroll
    for (int kk = 0; kk < 2; ++kk)
      #pragma unroll
      for (int m2 = 0; m2 < 4; ++m2)
        #pragma unroll
        for (int n2 = 0; n2 < 2; ++n2)
          o[MQH*4+m2][NQH*2+n2] = __builtin_amdgcn_mfma_f32_16x16x32_f16(
              af[m2][kk], bf[n2][kk], o[MQH*4+m2][NQH*2+n2], 0,0,0);
    __builtin_amdgcn_s_setprio(0);
  };

  #define BAR   __builtin_amdgcn_s_barrier()
  #define LGKM0 asm volatile("s_waitcnt lgkmcnt(0)" ::: "memory")
  #define VMC(N) asm volatile("s_waitcnt vmcnt(" #N ")" ::: "memory")

  // prologue: b0 all 4 units (K-step 0), b1 A0+B0 (K-step 1)
  STAGEA(0,0,0); STAGEB(0,0,0); STAGEA(0,1,0); STAGEB(0,1,0);
  STAGEA(1,0,1); STAGEB(1,0,1);
  VMC(4); BAR;

  #pragma unroll 1
  for (int it = 0; it < 8; ++it){
    const int k1 = 2*it + 1;
    const int k2 = (2*it + 2) & 15;   // tail iters: harmless in-bounds dummy
    const int k3 = (2*it + 3) & 15;

    // P1: quadrant (0,0) of K-step 2it (buf0)
    LOADA(0,0); LOADB(0,0,bfa);
    STAGEA(1,1,k1);
    BAR; LGKM0;
    QUAD(0,0,bfa);
    VMC(6); BAR;
    // P2: (0,1)
    LOADB(0,1,bfb);
    STAGEB(1,1,k1);
    BAR; LGKM0;
    QUAD(0,1,bfb);
    VMC(10); BAR;
    // P3: (1,0)
    LOADA(0,1);
    STAGEA(0,0,k2);
    BAR; LGKM0;
    QUAD(1,0,bfa);
    VMC(10); BAR;
    // P4: (1,1)
    STAGEB(0,0,k2);
    BAR; LGKM0;
    QUAD(1,1,bfb);
    VMC(8); BAR;
    // P5: quadrant (0,0) of K-step 2it+1 (buf1)
    LOADA(1,0); LOADB(1,0,bfa);
    STAGEA(0,1,k2);
    BAR; LGKM0;
    QUAD(0,0,bfa);
    VMC(6); BAR;
    // P6: (0,1)
    LOADB(1,1,bfb);
    STAGEB(0,1,k2);
    BAR; LGKM0;
    QUAD(0,1,bfb);
    VMC(10); BAR;
    // P7: (1,0)
    LOADA(1,1);
    STAGEA(1,0,k3);
    BAR; LGKM0;
    QUAD(1,0,bfa);
    VMC(10); BAR;
    // P8: (1,1)
    STAGEB(1,0,k3);
    BAR; LGKM0;
    QUAD(1,1,bfb);
    VMC(8); BAR;
  }

  asm volatile("s_waitcnt vmcnt(0)" ::: "memory");
  __syncthreads();

  // epilogue: exp -> bf16 P, via LDS in two 128-row rounds. Pimg stride 264.
  unsigned short* Pimg = (unsigned short*)smem;
  const int qq = tid >> 2, rem = tid & 3;
  #pragma unroll 1
  for (int mh = 0; mh < 2; ++mh){
    if (wr == mh){
      #pragma unroll
      for (int mi = 0; mi < 8; ++mi)
        #pragma unroll
        for (int ni = 0; ni < 4; ++ni){
          f32x4 sv = o[mi][ni];
          #pragma unroll
          for (int cc = 0; cc < 4; ++cc){
            float p = exp2f(fmaf(sv[cc], L2E, -SHIFT_L2E));
            int ql = mi*16 + quad*4 + cc;
            int jl = wc*64 + ni*16 + l16;
            Pimg[ql*264 + jl] = bf16rne(p);
          }
        }
    }
    __syncthreads();
    {
      const unsigned short* srcr = Pimg + qq*264 + rem*64;
      unsigned short* dst = Pt
        + ((size_t)((b*16 + qt2*2 + mh)*32 + (jt2*4 + rem)))*8192 + qq*64;
      #pragma unroll
      for (int ch = 0; ch < 8; ++ch){
        uint4 v = *(const uint4*)(srcr + ch*8);
        *(uint4*)(dst + ((ch ^ (qq & 7))*8)) = v;
      }
    }
    __syncthreads();
  }
  #undef BAR
  #undef LGKM0
  #undef VMC
}

// =================== Kernel B (tier-1): O = (P*V)/rowsum(P) ===================

__global__ __launch_bounds__(256, 2)
void gemm_o(const unsigned short* __restrict__ Pt,
            const unsigned short* __restrict__ VTt, float* __restrict__ Og)
{
  extern __shared__ char smem[];   // 65536: [2][ P:16384 | V:16384 ]

  const int tid  = threadIdx.x;
  const int w    = tid >> 6, lane = tid & 63;
  const int l16  = lane & 15, quad = lane >> 4;
  const int wr   = w >> 1, wc = w & 1;

  // b -> XCD pair {2b,2b+1}; 8qt x 8dt supertile per XCD
  const int x = blockIdx.x & 7;
  const int i = blockIdx.x >> 3;          // 0..63
  const int b  = x >> 1;
  const int qt = (x & 1)*8 + (i >> 3);
  const int dt = i & 7;
  const int q0 = qt << 7, d0 = dt << 7;

  const char* pslab = (const char*)Pt  + (size_t)(b*16 + qt)*32*16384;
  const char* vslab = (const char*)VTt + (size_t)((b*8 + dt)*32)*16384;
  const int gofs = w*4096 + lane*16;      // byte-linear within 16KB tile
  const int lbase = w*4096;               // wave-uniform LDS base

  f32x4 o[4][4], lacc[4];
  #pragma unroll
  for (int mi = 0; mi < 4; ++mi){
    #pragma unroll
    for (int ni = 0; ni < 4; ++ni) o[mi][ni] = (f32x4){0.f,0.f,0.f,0.f};
    lacc[mi] = (f32x4){0.f,0.f,0.f,0.f};
  }
  s16x8 ones;
  #pragma unroll
  for (int j = 0; j < 8; ++j) ones[j] = (short)0x3F80;

  {
    char* pb = smem;
    char* vb = smem + 16384;
    #pragma unroll
    for (int i4 = 0; i4 < 4; ++i4){
      async16(pslab + gofs + i4*1024, pb + lbase + i4*1024);
      async16(vslab + gofs + i4*1024, vb + lbase + i4*1024);
    }
  }

  for (int kt = 0; kt < 32; ++kt){
    const int c = kt & 1;
    __syncthreads();
    if (kt < 31){
      char* pb = smem + (c^1)*32768;
      char* vb = pb + 16384;
      const char* ps = pslab + (size_t)(kt+1)*16384;
      const char* vs = vslab + (size_t)(kt+1)*16384;
      #pragma unroll
      for (int i4 = 0; i4 < 4; ++i4){
        async16(ps + gofs + i4*1024, pb + lbase + i4*1024);
        async16(vs + gofs + i4*1024, vb + lbase + i4*1024);
      }
    }
    const short* Pc = (const short*)(smem + c*32768);
    const short* Vc = Pc + 8192;
    #pragma unroll
    for (int kh = 0; kh < 2; ++kh){
      const int pos = ((kh*4 + quad) ^ (l16 & 7)) * 8;
      s16x8 af[4], bfr[4];
      #pragma unroll
      for (int mi = 0; mi < 4; ++mi)
        af[mi] = *(const s16x8*)(Pc + (wr*64 + mi*16 + l16)*64 + pos);
      #pragma unroll
      for (int ni = 0; ni < 4; ++ni)
        bfr[ni] = *(const s16x8*)(Vc + (wc*64 + ni*16 + l16)*64 + pos);
      #pragma unroll
      for (int mi = 0; mi < 4; ++mi){
        #pragma unroll
        for (int ni = 0; ni < 4; ++ni)
          o[mi][ni] = __builtin_amdgcn_mfma_f32_16x16x32_bf16(af[mi], bfr[ni], o[mi][ni], 0,0,0);
        lacc[mi] = __builtin_amdgcn_mfma_f32_16x16x32_bf16(af[mi], ones, lacc[mi], 0,0,0);
      }
    }
  }

  float* outb = Og + ((size_t)(b*SQ + q0))*DD + d0;
  #pragma unroll
  for (int mi = 0; mi < 4; ++mi){
    f32x4 inv;
    #pragma unroll
    for (int cc = 0; cc < 4; ++cc) inv[cc] = 1.0f / lacc[mi][cc];
    #pragma unroll
    for (int ni = 0; ni < 4; ++ni)
      #pragma unroll
      for (int cc = 0; cc < 4; ++cc){
        int row = wr*64 + mi*16 + quad*4 + cc;
        int col = wc*64 + ni*16 + l16;
        outb[(size_t)row*DD + col] = o[mi][ni][cc] * inv[cc];
      }
  }
}

// =================== Kernel B (tier-2): R5 reg-transpose gemm_pv ===================

#define VTDW 34

__global__ __launch_bounds__(512, 4)
void gemm_pv(const float* __restrict__ Vg, const unsigned short* __restrict__ Pt,
             float* __restrict__ Og)
{
  extern __shared__ char smem[];          // 68096 B
  char*  Pb     = smem;
  char*  Vt     = smem + 32768;
  float* linv_s = (float*)(smem + 32768 + 2*17408);

  const int tid  = threadIdx.x;
  const int w    = tid >> 6, lane = tid & 63;
  const int l16  = lane & 15, quad = lane >> 4;
  const int wr   = w >> 2, wc = w & 3;

  const int bid = blockIdx.x;
  const int b  = bid >> 7;
  const int r  = bid & 127;
  const int qt = r >> 3, dt = r & 7;
  const int q0 = qt << 7, d0 = dt << 7;

  const int sa = tid & 31;
  const int sR = tid >> 5;
  const float* vsrc = Vg + ((size_t)(b*SK + 4*sR))*DD + d0 + 4*sa;

  const char* ptbase = (const char*)Pt + ((size_t)((b*16 + qt)*32))*16384;
  char* ldsA = Pb + ((tid >> 6) << 10);

  f32x4 vl[4];
  #pragma unroll
  for (int i = 0; i < 4; ++i)
    vl[i] = *(const f32x4*)(vsrc + (size_t)i*DD);
  async16(ptbase + tid*16,        ldsA);
  async16(ptbase + 8192 + tid*16, ldsA + 8192);

  s16x8 ones;
  #pragma unroll
  for (int i = 0; i < 8; ++i) ones[i] = (short)0x3F80;

  f32x4 o[4][2], lacc[4];
  #pragma unroll
  for (int mi = 0; mi < 4; ++mi){
    o[mi][0] = (f32x4){0.f,0.f,0.f,0.f};
    o[mi][1] = (f32x4){0.f,0.f,0.f,0.f};
    lacc[mi] = (f32x4){0.f,0.f,0.f,0.f};
  }

  for (int kt = 0; kt < 32; ++kt){
    const int c = kt & 1;
    char* Vc = Vt + c*17408;
    #pragma unroll
    for (int j = 0; j < 4; ++j){
      s16x4 t4 = { (short)bf16rne(vl[0][j]), (short)bf16rne(vl[1][j]),
                   (short)bf16rne(vl[2][j]), (short)bf16rne(vl[3][j]) };
      int d  = 4*sa + j;
      int dw = VTDW*d + 4*((sR >> 1) ^ (sa & 7)) + 2*(sR & 1);
      *(s16x4*)(Vc + dw*4) = t4;
    }
    __syncthreads();
    if (kt < 31){
      const float* vn = vsrc + (size_t)(kt+1)*64*DD;
      #pragma unroll
      for (int i = 0; i < 4; ++i)
        vl[i] = *(const f32x4*)(vn + (size_t)i*DD);
      char* ldsN = Pb + (c^1)*16384 + ((tid >> 6) << 10);
      const char* pn = ptbase + (size_t)(kt+1)*16384;
      async16(pn + tid*16,        ldsN);
      async16(pn + 8192 + tid*16, ldsN + 8192);
    }
    const char* Ac  = Pb + c*16384;
    const char* Vcc = Vt + c*17408;
    #pragma unroll
    for (int kh = 0; kh < 2; ++kh){
      s16x8 af[4];
      #pragma unroll
      for (int mi = 0; mi < 4; ++mi){
        int row = wr*64 + mi*16 + l16;
        af[mi] = *(const s16x8*)(Ac + row*128 + 16*((4*kh + quad) ^ (l16 & 7)));
      }
      s16x8 bfr[2];
      #pragma unroll
      for (int ni = 0; ni < 2; ++ni){
        int d  = wc*32 + ni*16 + l16;
        int cpv = (4*kh + quad) ^ ((d >> 2) & 7);
        const char* base = Vcc + (VTDW*d + 4*cpv)*4;
        s16x4 lo = *(const s16x4*)(base);
        s16x4 hi = *(const s16x4*)(base + 8);
        bfr[ni] = __builtin_shufflevector(lo, hi, 0,1,2,3,4,5,6,7);
      }
      #pragma unroll
      for (int mi = 0; mi < 4; ++mi){
        o[mi][0] = __builtin_amdgcn_mfma_f32_16x16x32_bf16(af[mi], bfr[0], o[mi][0], 0,0,0);
        o[mi][1] = __builtin_amdgcn_mfma_f32_16x16x32_bf16(af[mi], bfr[1], o[mi][1], 0,0,0);
        lacc[mi] = __builtin_amdgcn_mfma_f32_16x16x32_bf16(af[mi], ones,   lacc[mi], 0,0,0);
      }
    }
  }

  if (wc == 0 && l16 == 0){
    #pragma unroll
    for (int mi = 0; mi < 4; ++mi){
      f32x4 inv;
      #pragma unroll
      for (int cc = 0; cc < 4; ++cc) inv[cc] = 1.0f / lacc[mi][cc];
      *(f32x4*)(linv_s + wr*64 + mi*16 + quad*4) = inv;
    }
  }
  __syncthreads();

  float* outb = Og + ((size_t)(b*SQ + q0))*DD + d0;
  #pragma unroll
  for (int mi = 0; mi < 4; ++mi){
    f32x4 inv = *(const f32x4*)(linv_s + wr*64 + mi*16 + quad*4);
    #pragma unroll
    for (int ni = 0; ni < 2; ++ni)
      #pragma unroll
      for (int cc = 0; cc < 4; ++cc){
        int row = wr*64 + mi*16 + quad*4 + cc;
        int col = wc*32 + ni*16 + l16;
        outb[(size_t)row*DD + col] = o[mi][ni][cc] * inv[cc];
      }
  }
}

// =================== tier-3 fallback (R3 fused) ===================

#define BM 32
#define BN 32
#define NKT (SK / BN)
#define VS 1032
#define VTS3 34
#define PS 40

__device__ __forceinline__ float red16_max(float v){
  v = fmaxf(v, __shfl_xor(v, 1, 64));
  v = fmaxf(v, __shfl_xor(v, 2, 64));
  v = fmaxf(v, __shfl_xor(v, 4, 64));
  v = fmaxf(v, __shfl_xor(v, 8, 64));
  return v;
}
__device__ __forceinline__ float red16_sum(float v){
  v += __shfl_xor(v, 1, 64);
  v += __shfl_xor(v, 2, 64);
  v += __shfl_xor(v, 4, 64);
  v += __shfl_xor(v, 8, 64);
  return v;
}

__global__ __launch_bounds__(512, 2)
void luong_attn_r3(const float* __restrict__ Qg, const float* __restrict__ Vg,
                   float* __restrict__ Og)
{
  extern __shared__ char smem[];
  f16*   Vh     = (f16*)smem;
  f16*   Vt     = Vh + BN*VS;
  f16*   Ptl    = Vt + DD*VTS3;
  float* Sp     = (float*)(Ptl + BM*PS);
  float* alphas = Sp + 2*8*64*4;
  float* linv_s = alphas + BM;

  const int tid  = threadIdx.x;
  const int w    = tid >> 6;
  const int lane = tid & 63;
  const int l16  = lane & 15;
  const int quad = lane >> 4;

  const int i_   = blockIdx.x;
  const int b    = (i_ & 7) >> 1;
  const int q0   = (((i_ >> 3) << 1) | (i_ & 1)) * BM;

  const int jg  = tid >> 7;
  const int dgp = tid & 127;
  const int j0  = jg * 8;
  const int d0  = dgp * 8;
  const int vtc = (jg ^ ((dgp >> 2) & 3)) * 8;
  const int dh = w >> 1;

  f16x8 qf[2][8];
  #pragma unroll
  for (int rb = 0; rb < 2; ++rb){
    const float4* qrow = (const float4*)(Qg + ((size_t)b*SQ + q0 + rb*16 + l16)*DD);
    #pragma unroll
    for (int kc = 0; kc < 8; ++kc){
      int fi = dh*64 + kc*8 + quad*2;
      float4 xx = qrow[fi], yy = qrow[fi+1];
      qf[rb][kc] = (f16x8){ (f16)xx.x,(f16)xx.y,(f16)xx.z,(f16)xx.w,
                            (f16)yy.x,(f16)yy.y,(f16)yy.z,(f16)yy.w };
    }
  }

  f32x4 o[2][8];
  #pragma unroll
  for (int r2 = 0; r2 < 2; ++r2)
    #pragma unroll
    for (int t = 0; t < 8; ++t)
      o[r2][t] = (f32x4){0.f,0.f,0.f,0.f};

  float mreg[2][4], lpart[2][4];
  #pragma unroll
  for (int r2 = 0; r2 < 2; ++r2)
    #pragma unroll
    for (int cc = 0; cc < 4; ++cc){ mreg[r2][cc] = -3.0e30f; lpart[r2][cc] = 0.f; }

  const float* vb32 = Vg + (size_t)b*SK*DD;
  float4 p32a[8], p32b[8];
  #pragma unroll
  for (int r2 = 0; r2 < 8; ++r2){
    const float4* p4 = (const float4*)(vb32 + (size_t)(j0 + r2)*DD + d0);
    p32a[r2] = p4[0]; p32b[r2] = p4[1];
  }

  for (int kt = 0; kt < NKT; ++kt){
    {
      f16x8 h[8];
      #pragma unroll
      for (int r2 = 0; r2 < 8; ++r2){
        float4 xx = p32a[r2], yy = p32b[r2];
        h[r2] = (f16x8){ (f16)xx.x,(f16)xx.y,(f16)xx.z,(f16)xx.w,
                         (f16)yy.x,(f16)yy.y,(f16)yy.z,(f16)yy.w };
        *(f16x8*)(Vh + (j0 + r2)*VS + d0) = h[r2];
      }
      #pragma unroll
      for (int i = 0; i < 8; ++i){
        f16x8 t = (f16x8){ h[0][i], h[1][i], h[2][i], h[3][i],
                           h[4][i], h[5][i], h[6][i], h[7][i] };
        *(f16x8*)(Vt + (size_t)(d0 + i)*VTS3 + vtc) = t;
      }
    }
    __syncthreads();

    f32x4 sacc0 = (f32x4){0.f,0.f,0.f,0.f};
    f32x4 sacc1 = (f32x4){0.f,0.f,0.f,0.f};
    {
      const int cb = w & 1;
      const f16* vb = Vh + (cb*16 + l16)*VS + dh*256 + quad*8;
      #pragma unroll
      for (int kc = 0; kc < 8; ++kc){
        f16x8 bb = *(const f16x8*)(vb + kc*32);
        sacc0 = __builtin_amdgcn_mfma_f32_16x16x32_f16(qf[0][kc], bb, sacc0, 0,0,0);
        sacc1 = __builtin_amdgcn_mfma_f32_16x16x32_f16(qf[1][kc], bb, sacc1, 0,0,0);
      }
    }
    *(f32x4*)(Sp + ((0*8 + w)*64 + lane)*4) = sacc0;
    *(f32x4*)(Sp + ((1*8 + w)*64 + lane)*4) = sacc1;
    __syncthreads();

    if (kt + 1 < NKT){
      const float* rowp = vb32 + (size_t)((kt+1)*BN + j0)*DD + d0;
      #pragma unroll
      for (int r2 = 0; r2 < 8; ++r2){
        const float4* p4 = (const float4*)(rowp + (size_t)r2*DD);
        p32a[r2] = p4[0]; p32b[r2] = p4[1];
      }
    }

    float av[2][4];
    if (w < 2){
      f32x4 sh[2][2];
      #pragma unroll
      for (int rb = 0; rb < 2; ++rb)
        #pragma unroll
        for (int hf = 0; hf < 2; ++hf){
          f32x4 acc = *(const f32x4*)(Sp + ((rb*8 + hf  )*64 + lane)*4);
          acc      += *(const f32x4*)(Sp + ((rb*8 + hf+2)*64 + lane)*4);
          acc      += *(const f32x4*)(Sp + ((rb*8 + hf+4)*64 + lane)*4);
          acc      += *(const f32x4*)(Sp + ((rb*8 + hf+6)*64 + lane)*4);
          sh[rb][hf] = acc;
        }
      #pragma unroll
      for (int rb = 0; rb < 2; ++rb){
        #pragma unroll
        for (int cc = 0; cc < 4; ++cc){
          float s0 = sh[rb][0][cc], s1 = sh[rb][1][cc];
          float mrow = red16_max(fmaxf(s0, s1));
          float mold = mreg[rb][cc];
          float mnew = fmaxf(mold, mrow);
          float alpha = exp2f((mold - mnew)*L2E);
          float p0 = exp2f((s0 - mnew)*L2E);
          float p1 = exp2f((s1 - mnew)*L2E);
          lpart[rb][cc] = lpart[rb][cc]*alpha + red16_sum(p0 + p1);
          mreg[rb][cc]  = mnew;
          av[rb][cc]    = alpha;
          int row = rb*16 + quad*4 + cc;
          Ptl[row*PS + w*16 + l16] = (f16)(w == 0 ? p0 : p1);
          if (w == 0 && l16 == 0) alphas[row] = alpha;
        }
      }
    }
    __syncthreads();

    if (w >= 2){
      #pragma unroll
      for (int r2 = 0; r2 < 2; ++r2)
        #pragma unroll
        for (int cc = 0; cc < 4; ++cc)
          av[r2][cc] = alphas[r2*16 + quad*4 + cc];
    }
    {
      bool ne = false;
      #pragma unroll
      for (int r2 = 0; r2 < 2; ++r2)
        #pragma unroll
        for (int cc = 0; cc < 4; ++cc)
          ne |= (av[r2][cc] != 1.0f);
      if (__ballot(ne) != 0ull){
        #pragma unroll
        for (int r2 = 0; r2 < 2; ++r2)
          #pragma unroll
          for (int t = 0; t < 8; ++t)
            #pragma unroll
            for (int cc = 0; cc < 4; ++cc)
              o[r2][t][cc] *= av[r2][cc];
      }
    }
    {
      f16x8 ap0 = *(const f16x8*)(Ptl + (0*16 + l16)*PS + quad*8);
      f16x8 ap1 = *(const f16x8*)(Ptl + (1*16 + l16)*PS + quad*8);
      #pragma unroll
      for (int t = 0; t < 8; ++t){
        int vrow = w*128 + t*16 + l16;
        int pq   = (quad ^ ((t >> 1) & 3)) * 8;
        f16x8 bv = *(const f16x8*)(Vt + (size_t)vrow*VTS3 + pq);
        o[0][t] = __builtin_amdgcn_mfma_f32_16x16x32_f16(ap0, bv, o[0][t], 0,0,0);
        o[1][t] = __builtin_amdgcn_mfma_f32_16x16x32_f16(ap1, bv, o[1][t], 0,0,0);
      }
    }
    __syncthreads();
  }

  if (w == 0 && l16 == 0){
    #pragma unroll
    for (int rb = 0; rb < 2; ++rb)
      #pragma unroll
      for (int cc = 0; cc < 4; ++cc)
        linv_s[rb*16 + quad*4 + cc] = 1.0f / lpart[rb][cc];
  }
  __syncthreads();

  float linv[2][4];
  #pragma unroll
  for (int r2 = 0; r2 < 2; ++r2)
    #pragma unroll
    for (int cc = 0; cc < 4; ++cc)
      linv[r2][cc] = linv_s[r2*16 + quad*4 + cc];

  float* outp = Og + ((size_t)b*SQ + q0)*DD;
  #pragma unroll
  for (int r2 = 0; r2 < 2; ++r2)
    #pragma unroll
    for (int t = 0; t < 8; ++t)
      #pragma unroll
      for (int cc = 0; cc < 4; ++cc){
        int row = r2*16 + quad*4 + cc;
        int col = w*128 + t*16 + l16;
        outp[(size_t)row*DD + col] = o[r2][t][cc] * linv[r2][cc];
      }
}

// =================== launch ===================

extern "C" void kernel_launch(void* const* d_in, const int* in_sizes, int n_in,
                              void* d_out, int out_size, void* d_ws, size_t ws_size,
                              hipStream_t stream)
{
  const float* Qg = (const float*)d_in[0];
  const float* Vg = (const float*)d_in[1];
  float* Og = (float*)d_out;

  const size_t PB  = (size_t)NB*SQ*SK*2;   // 32 MiB (P)
  const size_t VTB = (size_t)NB*DD*SK*2;   // 16 MiB (VTt)

  if (ws_size >= PB && d_ws != nullptr){
    unsigned short* P = (unsigned short*)d_ws;
    f16* Q16 = (f16*)d_out;                    // d_out hosts Q16+V16 until gemm_o
    f16* V16 = Q16 + (size_t)NB*SQ*DD;
    const bool tier1 = (ws_size >= PB + VTB);

    (void)hipFuncSetAttribute(reinterpret_cast<const void*>(gemm_s),
                              hipFuncAttributeMaxDynamicSharedMemorySize, 131072);
    if (tier1){
      unsigned short* VTt = (unsigned short*)((char*)d_ws + PB);
      (void)hipFuncSetAttribute(reinterpret_cast<const void*>(gemm_o),
                                hipFuncAttributeMaxDynamicSharedMemorySize, 65536);
      prep_all<<<dim3(6144), dim3(256), 0, stream>>>(Qg, Vg, Q16, V16, VTt);
      gemm_s<<<dim3(256), dim3(512), 131072, stream>>>(Q16, V16, P);
      gemm_o<<<dim3(512),  dim3(256), 65536, stream>>>(P, VTt, Og);
    } else {
      (void)hipFuncSetAttribute(reinterpret_cast<const void*>(gemm_pv),
                                hipFuncAttributeMaxDynamicSharedMemorySize, 68096);
      cvt_f16<<<dim3(4096), dim3(256), 0, stream>>>(Qg, Q16);
      cvt_f16<<<dim3(4096), dim3(256), 0, stream>>>(Vg, V16);
      gemm_s<<<dim3(256), dim3(512), 131072, stream>>>(Q16, V16, P);
      gemm_pv<<<dim3(512), dim3(512), 68096, stream>>>(Vg, P, Og);
    }
  } else {
    size_t smem = (size_t)BN*VS*sizeof(f16)
                + (size_t)DD*VTS3*sizeof(f16)
                + (size_t)BM*PS*sizeof(f16)
                + (size_t)(2*8*64*4)*sizeof(float)
                + (size_t)(BM + BM)*sizeof(float);
    (void)hipFuncSetAttribute(reinterpret_cast<const void*>(luong_attn_r3),
                              hipFuncAttributeMaxDynamicSharedMemorySize, (int)smem);
    luong_attn_r3<<<dim3(NB*(SQ/BM)), dim3(512), smem, stream>>>(Qg, Vg, Og);
  }
}

// Round 2
// 184.263 us; speedup vs baseline: 1.0181x; 1.0097x over previous
//
#include <hip/hip_runtime.h>

// Luong attention: B=4, Q=K=2048, D=1024, fp32 in/out.
// R9: gemm_s 256x256 BK=64 8-wave, merged fat phases: 2 phases/K-step,
// 32 MFMA per barrier-pair (was 16), counted vmcnt(8) publish discipline.
// gemm_o / prep_all / gemm_pv / tier-3 unchanged.

#define SQ 2048
#define SK 2048
#define DD 1024
#define NB 4

typedef _Float16 f16;
typedef _Float16 f16x8 __attribute__((ext_vector_type(8)));
typedef _Float16 f16x4 __attribute__((ext_vector_type(4)));
typedef short s16x8 __attribute__((ext_vector_type(8)));
typedef short s16x4 __attribute__((ext_vector_type(4)));
typedef float f32x4 __attribute__((ext_vector_type(4)));

#define L2E 1.44269504f
#define SHIFT_L2E 184.664965f   // 128 * log2(e)

__device__ __forceinline__ unsigned short bf16rne(float x){
  unsigned u = __float_as_uint(x);
  return (unsigned short)((u + 0x7FFFu + ((u >> 16) & 1u)) >> 16);
}
__device__ __forceinline__ void async16(const void* g, void* l){
  __builtin_amdgcn_global_load_lds((const __attribute__((address_space(1))) void*)g,
                                   (__attribute__((address_space(3))) void*)l,
                                   16, 0, 0);
}

// =================== prepass: Q16 + V16 + tiled VTt, one kernel ===================
// VTt layout: [b][dt:8][kt:32][d:128][ch:8 @ pos ch^(d&7)][8 bf16] -> 16KB tiles.

__global__ __launch_bounds__(256)
void prep_all(const float* __restrict__ Qg, const float* __restrict__ Vg,
              f16* __restrict__ Q16, f16* __restrict__ V16,
              unsigned short* __restrict__ VTt)
{
  __shared__ float T[64][65];
  const int bid = blockIdx.x;
  const int tid = threadIdx.x;

  if (bid >= 2048){
    // ---- Q part: f32 -> f16, 8 elems/thread ----
    size_t i = (size_t)(bid - 2048) * 256 + tid;
    const float4* p = (const float4*)Qg + i*2;
    float4 a = p[0], b = p[1];
    f16x8 h = { (f16)a.x,(f16)a.y,(f16)a.z,(f16)a.w,
                (f16)b.x,(f16)b.y,(f16)b.z,(f16)b.w };
    *(f16x8*)(Q16 + i*8) = h;
    return;
  }

  // ---- V part: 64j x 64d tile -> V16 (row-major f16) + VTt (tiled bf16) ----
  const int b  = bid >> 9;
  const int jt = (bid >> 4) & 31;
  const int dt16 = bid & 15;
  const int j0 = jt*64, d0 = dt16*64;
  const int c4 = (tid & 15) * 4;
  const int jl = tid >> 4;

  const float* src = Vg + ((size_t)b*SK + j0)*DD + d0;
  #pragma unroll
  for (int it = 0; it < 4; ++it){
    int j = jl + it*16;
    float4 x = *(const float4*)(src + (size_t)j*DD + c4);
    f16x4 h = {(f16)x.x,(f16)x.y,(f16)x.z,(f16)x.w};
    *(f16x4*)(V16 + ((size_t)b*SK + j0 + j)*DD + d0 + c4) = h;
    T[j][c4+0]=x.x; T[j][c4+1]=x.y; T[j][c4+2]=x.z; T[j][c4+3]=x.w;
  }
  __syncthreads();

  const int dl = tid >> 2;            // 0..63
  const int js = (tid & 3) * 16;      // 16 k's = chunks ch0, ch0+1 of BK=64 tile jt
  unsigned short tmp[16];
  #pragma unroll
  for (int i = 0; i < 16; ++i)
    tmp[i] = bf16rne(T[js+i][dl]);

  const int d    = d0 + dl;
  const int dt   = d >> 7;
  const int dloc = d & 127;
  const int ch0  = js >> 3;           // 0,2,4,6
  unsigned short* row = VTt + ((size_t)((b*8 + dt)*32 + jt)*128 + dloc)*64;
  *(uint4*)(row + (( ch0   ^ (dloc & 7)) * 8)) = *(uint4*)&tmp[0];
  *(uint4*)(row + (((ch0+1) ^ (dloc & 7)) * 8)) = *(uint4*)&tmp[8];
}

// tier-2 prepass
__global__ __launch_bounds__(256) void cvt_f16(const float* __restrict__ src,
                                               f16* __restrict__ dst)
{
  size_t i = (size_t)blockIdx.x * 256 + threadIdx.x;
  const float4* p = (const float4*)src + i*2;
  float4 a = p[0], b = p[1];
  f16x8 h = { (f16)a.x,(f16)a.y,(f16)a.z,(f16)a.w,
              (f16)b.x,(f16)b.y,(f16)b.z,(f16)b.w };
  *(f16x8*)(dst + i*8) = h;
}

// =================== Kernel A: P = exp(Q*V^T - 128), 256^2 fat-phase ===================
// Tile 256x256, BK=64, 8 waves (2M x 4N), per-wave 128x64 output.
// LDS 128KB: buf b at b*65536: A-u0(16K) A-u1(16K) B-u0(16K) B-u1(16K).
//   A-u0 = tile rows {0-63,128-191}; A-u1 = {64-127,192-255}
//   B-u0 = V rows {0-31,64-95,128-159,192-223}; B-u1 = +32
// Within a unit: 128 rows x 128B, chunk ch of row r at pos ch^(r&7)
// (swizzle on the GLOBAL source address; LDS dest linear).
// Fat-phase schedule, 2 phases per K-step k (buf p=k&1):
//  (k,0): read A0,B0,B1(p); stage A1[k+1]->p^1; BAR;lgkm0; 32 MFMA; vmcnt(8); BAR
//  (k,1): read A1(p); stage A0,B0,B1[k+2]->p; BAR;lgkm0; 32 MFMA; vmcnt(8); BAR
// Per-wave queue: prologue 14 loads, vmcnt(6); steady 8..14 outstanding;
// each vmcnt(8) drains exactly the unit published at the following barrier.
// P layout (unchanged): [b*16+qt][jc:32][q:128][chunk:8 @ pos ch^(q&7)][8 bf16]

__global__ __launch_bounds__(512, 2)
void gemm_s(const f16* __restrict__ Q16, const f16* __restrict__ V16,
            unsigned short* __restrict__ Pt)
{
  extern __shared__ char smem[];                 // 131072 B

  const int tid  = threadIdx.x;
  const int w    = tid >> 6, lane = tid & 63;
  const int l16  = lane & 15, quad = lane >> 4;
  const int wr   = w >> 2;            // 0..1  M half
  const int wc   = w & 3;             // 0..3  N quarter

  // XCD supertile: b -> XCD pair, 8qt x 4jt per XCD
  const int x = blockIdx.x & 7;
  const int s = blockIdx.x >> 3;      // 0..31
  const int b   = x >> 1;
  const int h   = x & 1;
  const int qt2 = s >> 2;             // 0..7 (256-row Q tile)
  const int jt2 = h*4 + (s & 3);      // 0..7 (256-row V tile)

  const char* Abase = (const char*)(Q16 + ((size_t)b*SQ + qt2*256)*DD);
  const char* Bbase = (const char*)(V16 + ((size_t)b*SK + jt2*256)*DD);

  // per-lane staging source offsets (issue i covers unit element i*512+tid)
  int aoff0, aoff1, boff0, boff1;
  {
    int rp0 = tid >> 3;                       // row-in-unit, issue 0
    int c0  = (tid & 7) ^ (rp0 & 7);          // source chunk (pre-swizzle)
    aoff0 = (((rp0 >> 6)*128) + (rp0 & 63))*2048 + c0*16;
    boff0 = (((rp0 >> 5)*64 ) + (rp0 & 31))*2048 + c0*16;
    int rp1 = 64 + rp0;                       // issue 1
    int c1  = (tid & 7) ^ (rp1 & 7);
    aoff1 = (((rp1 >> 6)*128) + (rp1 & 63))*2048 + c1*16;
    boff1 = (((rp1 >> 5)*64 ) + (rp1 & 31))*2048 + c1*16;
  }

  const int aRdOff = (wr*64 + l16)*128;
  const int bRdOff = (wc*32 + l16)*128;
  const int pos0   = (quad ^ (l16 & 7)) * 16; // kk=0 chunk pos; kk=1 = pos0^64

  f32x4 o[8][4];
  #pragma unroll
  for (int mi = 0; mi < 8; ++mi)
    #pragma unroll
    for (int ni = 0; ni < 4; ++ni)
      o[mi][ni] = (f32x4){0.f,0.f,0.f,0.f};

  f16x8 af[4][2], bfa[2][2], bfb[2][2];

  auto STAGEA = [&](int BB, int U, int KS){
    char* lb = smem + BB*65536 + U*16384 + w*1024;
    const char* g = Abase + U*131072 + KS*128;
    async16(g + aoff0, lb);
    async16(g + aoff1, lb + 8192);
  };
  auto STAGEB = [&](int BB, int U, int KS){
    char* lb = smem + BB*65536 + 32768 + U*16384 + w*1024;
    const char* g = Bbase + U*65536 + KS*128;
    async16(g + boff0, lb);
    async16(g + boff1, lb + 8192);
  };
  auto LOADA = [&](int BB, int MQH){
    const char* ab = smem + BB*65536 + MQH*16384 + aRdOff;
    #pragma unroll
    for (int m2 = 0; m2 < 4; ++m2){
      af[m2][0] = *(const f16x8*)(ab + m2*2048 + pos0);
      af[m2][1] = *(const f16x8*)(ab + m2*2048 + (pos0 ^ 64));
    }
  };
  auto LOADB = [&](int BB, int NQH, f16x8 (*bf)[2]){
    const char* bb = smem + BB*65536 + 32768 + NQH*16384 + bRdOff;
    #pragma unroll
    for (int n2 = 0; n2 < 2; ++n2){
      bf[n2][0] = *(const f16x8*)(bb + n2*2048 + pos0);
      bf[n2][1] = *(const f16x8*)(bb + n2*2048 + (pos0 ^ 64));
    }
  };
  auto QUAD = [&](int MQH, int NQH, f16x8 (*bf)[2]){
    #pragma unroll
    for (int kk = 0; kk < 2; ++kk)
      #pragma unroll
      for (int m2 = 0; m2 < 4; ++m2)
        #pragma unroll
        for (int n2 = 0; n2 < 2; ++n2)
          o[MQH*4+m2][NQH*2+n2] = __builtin_amdgcn_mfma_f32_16x16x32_f16(
              af[m2][kk], bf[n2][kk], o[MQH*4+m2][NQH*2+n2], 0,0,0);
  };

  #define BAR   __builtin_amdgcn_s_barrier()
  #define LGKM0 asm volatile("s_waitcnt lgkmcnt(0)" ::: "memory")
  #define VMC(N) asm volatile("s_waitcnt vmcnt(" #N ")" ::: "memory")
  #define PRIO1 __builtin_amdgcn_s_setprio(1)
  #define PRIO0 __builtin_amdgcn_s_setprio(0)

  // prologue: all 4 units of K-step 0 (buf0), A0/B0/B1 of K-step 1 (buf1)
  STAGEA(0,0,0); STAGEB(0,0,0); STAGEB(0,1,0); STAGEA(0,1,0);
  STAGEA(1,0,1); STAGEB(1,0,1); STAGEB(1,1,1);
  VMC(6); BAR;

  #pragma unroll 1
  for (int k = 0; k < 16; ++k){
    const int p   = k & 1;
    const int kA1 = (k+1) & 15;   // A1 target K-step (tail: harmless dummy)
    const int kN  = (k+2) & 15;   // A0/B0/B1 target K-step

    // ---- phase (k,0): quadrants (0,0),(0,1) ----
    LOADA(p,0); LOADB(p,0,bfa); LOADB(p,1,bfb);
    STAGEA(p^1,1,kA1);
    BAR; LGKM0;
    PRIO1; QUAD(0,0,bfa); QUAD(0,1,bfb); PRIO0;
    VMC(8); BAR;

    // ---- phase (k,1): quadrants (1,0),(1,1) ----
    LOADA(p,1);
    STAGEA(p,0,kN); STAGEB(p,0,kN); STAGEB(p,1,kN);
    BAR; LGKM0;
    PRIO1; QUAD(1,0,bfa); QUAD(1,1,bfb); PRIO0;
    VMC(8); BAR;
  }

  asm volatile("s_waitcnt vmcnt(0)" ::: "memory");
  __syncthreads();

  // epilogue: exp -> bf16 P, via LDS in two 128-row rounds. Pimg stride 264.
  unsigned short* Pimg = (unsigned short*)smem;
  const int qq = tid >> 2, rem = tid & 3;
  #pragma unroll 1
  for (int mh = 0; mh < 2; ++mh){
    if (wr == mh){
      #pragma unroll
      for (int mi = 0; mi < 8; ++mi)
        #pragma unroll
        for (int ni = 0; ni < 4; ++ni){
          f32x4 sv = o[mi][ni];
          #pragma unroll
          for (int cc = 0; cc < 4; ++cc){
            float p = exp2f(fmaf(sv[cc], L2E, -SHIFT_L2E));
            int ql = mi*16 + quad*4 + cc;
            int jl = wc*64 + ni*16 + l16;
            Pimg[ql*264 + jl] = bf16rne(p);
          }
        }
    }
    __syncthreads();
    {
      const unsigned short* srcr = Pimg + qq*264 + rem*64;
      unsigned short* dst = Pt
        + ((size_t)((b*16 + qt2*2 + mh)*32 + (jt2*4 + rem)))*8192 + qq*64;
      #pragma unroll
      for (int ch = 0; ch < 8; ++ch){
        uint4 v = *(const uint4*)(srcr + ch*8);
        *(uint4*)(dst + ((ch ^ (qq & 7))*8)) = v;
      }
    }
    __syncthreads();
  }
  #undef BAR
  #undef LGKM0
  #undef VMC
  #undef PRIO1
  #undef PRIO0
}

// =================== Kernel B (tier-1): O = (P*V)/rowsum(P) ===================

__global__ __launch_bounds__(256, 2)
void gemm_o(const unsigned short* __restrict__ Pt,
            const unsigned short* __restrict__ VTt, float* __restrict__ Og)
{
  extern __shared__ char smem[];   // 65536: [2][ P:16384 | V:16384 ]

  const int tid  = threadIdx.x;
  const int w    = tid >> 6, lane = tid & 63;
  const int l16  = lane & 15, quad = lane >> 4;
  const int wr   = w >> 1, wc = w & 1;

  // b -> XCD pair {2b,2b+1}; 8qt x 8dt supertile per XCD
  const int x = blockIdx.x & 7;
  const int i = blockIdx.x >> 3;          // 0..63
  const int b  = x >> 1;
  const int qt = (x & 1)*8 + (i >> 3);
  const int dt = i & 7;
  const int q0 = qt << 7, d0 = dt << 7;

  const char* pslab = (const char*)Pt  + (size_t)(b*16 + qt)*32*16384;
  const char* vslab = (const char*)VTt + (size_t)((b*8 + dt)*32)*16384;
  const int gofs = w*4096 + lane*16;      // byte-linear within 16KB tile
  const int lbase = w*4096;               // wave-uniform LDS base

  f32x4 o[4][4], lacc[4];
  #pragma unroll
  for (int mi = 0; mi < 4; ++mi){
    #pragma unroll
    for (int ni = 0; ni < 4; ++ni) o[mi][ni] = (f32x4){0.f,0.f,0.f,0.f};
    lacc[mi] = (f32x4){0.f,0.f,0.f,0.f};
  }
  s16x8 ones;
  #pragma unroll
  for (int j = 0; j < 8; ++j) ones[j] = (short)0x3F80;

  {
    char* pb = smem;
    char* vb = smem + 16384;
    #pragma unroll
    for (int i4 = 0; i4 < 4; ++i4){
      async16(pslab + gofs + i4*1024, pb + lbase + i4*1024);
      async16(vslab + gofs + i4*1024, vb + lbase + i4*1024);
    }
  }

  for (int kt = 0; kt < 32; ++kt){
    const int c = kt & 1;
    __syncthreads();
    if (kt < 31){
      char* pb = smem + (c^1)*32768;
      char* vb = pb + 16384;
      const char* ps = pslab + (size_t)(kt+1)*16384;
      const char* vs = vslab + (size_t)(kt+1)*16384;
      #pragma unroll
      for (int i4 = 0; i4 < 4; ++i4){
        async16(ps + gofs + i4*1024, pb + lbase + i4*1024);
        async16(vs + gofs + i4*1024, vb + lbase + i4*1024);
      }
    }
    const short* Pc = (const short*)(smem + c*32768);
    const short* Vc = Pc + 8192;
    #pragma unroll
    for (int kh = 0; kh < 2; ++kh){
      const int pos = ((kh*4 + quad) ^ (l16 & 7)) * 8;
      s16x8 af[4], bfr[4];
      #pragma unroll
      for (int mi = 0; mi < 4; ++mi)
        af[mi] = *(const s16x8*)(Pc + (wr*64 + mi*16 + l16)*64 + pos);
      #pragma unroll
      for (int ni = 0; ni < 4; ++ni)
        bfr[ni] = *(const s16x8*)(Vc + (wc*64 + ni*16 + l16)*64 + pos);
      #pragma unroll
      for (int mi = 0; mi < 4; ++mi){
        #pragma unroll
        for (int ni = 0; ni < 4; ++ni)
          o[mi][ni] = __builtin_amdgcn_mfma_f32_16x16x32_bf16(af[mi], bfr[ni], o[mi][ni], 0,0,0);
        lacc[mi] = __builtin_amdgcn_mfma_f32_16x16x32_bf16(af[mi], ones, lacc[mi], 0,0,0);
      }
    }
  }

  float* outb = Og + ((size_t)(b*SQ + q0))*DD + d0;
  #pragma unroll
  for (int mi = 0; mi < 4; ++mi){
    f32x4 inv;
    #pragma unroll
    for (int cc = 0; cc < 4; ++cc) inv[cc] = 1.0f / lacc[mi][cc];
    #pragma unroll
    for (int ni = 0; ni < 4; ++ni)
      #pragma unroll
      for (int cc = 0; cc < 4; ++cc){
        int row = wr*64 + mi*16 + quad*4 + cc;
        int col = wc*64 + ni*16 + l16;
        outb[(size_t)row*DD + col] = o[mi][ni][cc] * inv[cc];
      }
  }
}

// =================== Kernel B (tier-2): R5 reg-transpose gemm_pv ===================

#define VTDW 34

__global__ __launch_bounds__(512, 4)
void gemm_pv(const float* __restrict__ Vg, const unsigned short* __restrict__ Pt,
             float* __restrict__ Og)
{
  extern __shared__ char smem[];          // 68096 B
  char*  Pb     = smem;
  char*  Vt     = smem + 32768;
  float* linv_s = (float*)(smem + 32768 + 2*17408);

  const int tid  = threadIdx.x;
  const int w    = tid >> 6, lane = tid & 63;
  const int l16  = lane & 15, quad = lane >> 4;
  const int wr   = w >> 2, wc = w & 3;

  const int bid = blockIdx.x;
  const int b  = bid >> 7;
  const int r  = bid & 127;
  const int qt = r >> 3, dt = r & 7;
  const int q0 = qt << 7, d0 = dt << 7;

  const int sa = tid & 31;
  const int sR = tid >> 5;
  const float* vsrc = Vg + ((size_t)(b*SK + 4*sR))*DD + d0 + 4*sa;

  const char* ptbase = (const char*)Pt + ((size_t)((b*16 + qt)*32))*16384;
  char* ldsA = Pb + ((tid >> 6) << 10);

  f32x4 vl[4];
  #pragma unroll
  for (int i = 0; i < 4; ++i)
    vl[i] = *(const f32x4*)(vsrc + (size_t)i*DD);
  async16(ptbase + tid*16,        ldsA);
  async16(ptbase + 8192 + tid*16, ldsA + 8192);

  s16x8 ones;
  #pragma unroll
  for (int i = 0; i < 8; ++i) ones[i] = (short)0x3F80;

  f32x4 o[4][2], lacc[4];
  #pragma unroll
  for (int mi = 0; mi < 4; ++mi){
    o[mi][0] = (f32x4){0.f,0.f,0.f,0.f};
    o[mi][1] = (f32x4){0.f,0.f,0.f,0.f};
    lacc[mi] = (f32x4){0.f,0.f,0.f,0.f};
  }

  for (int kt = 0; kt < 32; ++kt){
    const int c = kt & 1;
    char* Vc = Vt + c*17408;
    #pragma unroll
    for (int j = 0; j < 4; ++j){
      s16x4 t4 = { (short)bf16rne(vl[0][j]), (short)bf16rne(vl[1][j]),
                   (short)bf16rne(vl[2][j]), (short)bf16rne(vl[3][j]) };
      int d  = 4*sa + j;
      int dw = VTDW*d + 4*((sR >> 1) ^ (sa & 7)) + 2*(sR & 1);
      *(s16x4*)(Vc + dw*4) = t4;
    }
    __syncthreads();
    if (kt < 31){
      const float* vn = vsrc + (size_t)(kt+1)*64*DD;
      #pragma unroll
      for (int i = 0; i < 4; ++i)
        vl[i] = *(const f32x4*)(vn + (size_t)i*DD);
      char* ldsN = Pb + (c^1)*16384 + ((tid >> 6) << 10);
      const char* pn = ptbase + (size_t)(kt+1)*16384;
      async16(pn + tid*16,        ldsN);
      async16(pn + 8192 + tid*16, ldsN + 8192);
    }
    const char* Ac  = Pb + c*16384;
    const char* Vcc = Vt + c*17408;
    #pragma unroll
    for (int kh = 0; kh < 2; ++kh){
      s16x8 af[4];
      #pragma unroll
      for (int mi = 0; mi < 4; ++mi){
        int row = wr*64 + mi*16 + l16;
        af[mi] = *(const s16x8*)(Ac + row*128 + 16*((4*kh + quad) ^ (l16 & 7)));
      }
      s16x8 bfr[2];
      #pragma unroll
      for (int ni = 0; ni < 2; ++ni){
        int d  = wc*32 + ni*16 + l16;
        int cpv = (4*kh + quad) ^ ((d >> 2) & 7);
        const char* base = Vcc + (VTDW*d + 4*cpv)*4;
        s16x4 lo = *(const s16x4*)(base);
        s16x4 hi = *(const s16x4*)(base + 8);
        bfr[ni] = __builtin_shufflevector(lo, hi, 0,1,2,3,4,5,6,7);
      }
      #pragma unroll
      for (int mi = 0; mi < 4; ++mi){
        o[mi][0] = __builtin_amdgcn_mfma_f32_16x16x32_bf16(af[mi], bfr[0], o[mi][0], 0,0,0);
        o[mi][1] = __builtin_amdgcn_mfma_f32_16x16x32_bf16(af[mi], bfr[1], o[mi][1], 0,0,0);
        lacc[mi] = __builtin_amdgcn_mfma_f32_16x16x32_bf16(af[mi], ones,   lacc[mi], 0,0,0);
      }
    }
  }

  if (wc == 0 && l16 == 0){
    #pragma unroll
    for (int mi = 0; mi < 4; ++mi){
      f32x4 inv;
      #pragma unroll
      for (int cc = 0; cc < 4; ++cc) inv[cc] = 1.0f / lacc[mi][cc];
      *(f32x4*)(linv_s + wr*64 + mi*16 + quad*4) = inv;
    }
  }
  __syncthreads();

  float* outb = Og + ((size_t)(b*SQ + q0))*DD + d0;
  #pragma unroll
  for (int mi = 0; mi < 4; ++mi){
    f32x4 inv = *(const f32x4*)(linv_s + wr*64 + mi*16 + quad*4);
    #pragma unroll
    for (int ni = 0; ni < 2; ++ni)
      #pragma unroll
      for (int cc = 0; cc < 4; ++cc){
        int row = wr*64 + mi*16 + quad*4 + cc;
        int col = wc*32 + ni*16 + l16;
        outb[(size_t)row*DD + col] = o[mi][ni][cc] * inv[cc];
      }
  }
}

// =================== tier-3 fallback (R3 fused) ===================

#define BM 32
#define BN 32
#define NKT (SK / BN)
#define VS 1032
#define VTS3 34
#define PS 40

__device__ __forceinline__ float red16_max(float v){
  v = fmaxf(v, __shfl_xor(v, 1, 64));
  v = fmaxf(v, __shfl_xor(v, 2, 64));
  v = fmaxf(v, __shfl_xor(v, 4, 64));
  v = fmaxf(v, __shfl_xor(v, 8, 64));
  return v;
}
__device__ __forceinline__ float red16_sum(float v){
  v += __shfl_xor(v, 1, 64);
  v += __shfl_xor(v, 2, 64);
  v += __shfl_xor(v, 4, 64);
  v += __shfl_xor(v, 8, 64);
  return v;
}

__global__ __launch_bounds__(512, 2)
void luong_attn_r3(const float* __restrict__ Qg, const float* __restrict__ Vg,
                   float* __restrict__ Og)
{
  extern __shared__ char smem[];
  f16*   Vh     = (f16*)smem;
  f16*   Vt     = Vh + BN*VS;
  f16*   Ptl    = Vt + DD*VTS3;
  float* Sp     = (float*)(Ptl + BM*PS);
  float* alphas = Sp + 2*8*64*4;
  float* linv_s = alphas + BM;

  const int tid  = threadIdx.x;
  const int w    = tid >> 6;
  const int lane = tid & 63;
  const int l16  = lane & 15;
  const int quad = lane >> 4;

  const int i_   = blockIdx.x;
  const int b    = (i_ & 7) >> 1;
  const int q0   = (((i_ >> 3) << 1) | (i_ & 1)) * BM;

  const int jg  = tid >> 7;
  const int dgp = tid & 127;
  const int j0  = jg * 8;
  const int d0  = dgp * 8;
  const int vtc = (jg ^ ((dgp >> 2) & 3)) * 8;
  const int dh = w >> 1;

  f16x8 qf[2][8];
  #pragma unroll
  for (int rb = 0; rb < 2; ++rb){
    const float4* qrow = (const float4*)(Qg + ((size_t)b*SQ + q0 + rb*16 + l16)*DD);
    #pragma unroll
    for (int kc = 0; kc < 8; ++kc){
      int fi = dh*64 + kc*8 + quad*2;
      float4 xx = qrow[fi], yy = qrow[fi+1];
      qf[rb][kc] = (f16x8){ (f16)xx.x,(f16)xx.y,(f16)xx.z,(f16)xx.w,
                            (f16)yy.x,(f16)yy.y,(f16)yy.z,(f16)yy.w };
    }
  }

  f32x4 o[2][8];
  #pragma unroll
  for (int r2 = 0; r2 < 2; ++r2)
    #pragma unroll
    for (int t = 0; t < 8; ++t)
      o[r2][t] = (f32x4){0.f,0.f,0.f,0.f};

  float mreg[2][4], lpart[2][4];
  #pragma unroll
  for (int r2 = 0; r2 < 2; ++r2)
    #pragma unroll
    for (int cc = 0; cc < 4; ++cc){ mreg[r2][cc] = -3.0e30f; lpart[r2][cc] = 0.f; }

  const float* vb32 = Vg + (size_t)b*SK*DD;
  float4 p32a[8], p32b[8];
  #pragma unroll
  for (int r2 = 0; r2 < 8; ++r2){
    const float4* p4 = (const float4*)(vb32 + (size_t)(j0 + r2)*DD + d0);
    p32a[r2] = p4[0]; p32b[r2] = p4[1];
  }

  for (int kt = 0; kt < NKT; ++kt){
    {
      f16x8 h[8];
      #pragma unroll
      for (int r2 = 0; r2 < 8; ++r2){
        float4 xx = p32a[r2], yy = p32b[r2];
        h[r2] = (f16x8){ (f16)xx.x,(f16)xx.y,(f16)xx.z,(f16)xx.w,
                         (f16)yy.x,(f16)yy.y,(f16)yy.z,(f16)yy.w };
        *(f16x8*)(Vh + (j0 + r2)*VS + d0) = h[r2];
      }
      #pragma unroll
      for (int i = 0; i < 8; ++i){
        f16x8 t = (f16x8){ h[0][i], h[1][i], h[2][i], h[3][i],
                           h[4][i], h[5][i], h[6][i], h[7][i] };
        *(f16x8*)(Vt + (size_t)(d0 + i)*VTS3 + vtc) = t;
      }
    }
    __syncthreads();

    f32x4 sacc0 = (f32x4){0.f,0.f,0.f,0.f};
    f32x4 sacc1 = (f32x4){0.f,0.f,0.f,0.f};
    {
      const int cb = w & 1;
      const f16* vb = Vh + (cb*16 + l16)*VS + dh*256 + quad*8;
      #pragma unroll
      for (int kc = 0; kc < 8; ++kc){
        f16x8 bb = *(const f16x8*)(vb + kc*32);
        sacc0 = __builtin_amdgcn_mfma_f32_16x16x32_f16(qf[0][kc], bb, sacc0, 0,0,0);
        sacc1 = __builtin_amdgcn_mfma_f32_16x16x32_f16(qf[1][kc], bb, sacc1, 0,0,0);
      }
    }
    *(f32x4*)(Sp + ((0*8 + w)*64 + lane)*4) = sacc0;
    *(f32x4*)(Sp + ((1*8 + w)*64 + lane)*4) = sacc1;
    __syncthreads();

    if (kt + 1 < NKT){
      const float* rowp = vb32 + (size_t)((kt+1)*BN + j0)*DD + d0;
      #pragma unroll
      for (int r2 = 0; r2 < 8; ++r2){
        const float4* p4 = (const float4*)(rowp + (size_t)r2*DD);
        p32a[r2] = p4[0]; p32b[r2] = p4[1];
      }
    }

    float av[2][4];
    if (w < 2){
      f32x4 sh[2][2];
      #pragma unroll
      for (int rb = 0; rb < 2; ++rb)
        #pragma unroll
        for (int hf = 0; hf < 2; ++hf){
          f32x4 acc = *(const f32x4*)(Sp + ((rb*8 + hf  )*64 + lane)*4);
          acc      += *(const f32x4*)(Sp + ((rb*8 + hf+2)*64 + lane)*4);
          acc      += *(const f32x4*)(Sp + ((rb*8 + hf+4)*64 + lane)*4);
          acc      += *(const f32x4*)(Sp + ((rb*8 + hf+6)*64 + lane)*4);
          sh[rb][hf] = acc;
        }
      #pragma unroll
      for (int rb = 0; rb < 2; ++rb){
        #pragma unroll
        for (int cc = 0; cc < 4; ++cc){
          float s0 = sh[rb][0][cc], s1 = sh[rb][1][cc];
          float mrow = red16_max(fmaxf(s0, s1));
          float mold = mreg[rb][cc];
          float mnew = fmaxf(mold, mrow);
          float alpha = exp2f((mold - mnew)*L2E);
          float p0 = exp2f((s0 - mnew)*L2E);
          float p1 = exp2f((s1 - mnew)*L2E);
          lpart[rb][cc] = lpart[rb][cc]*alpha + red16_sum(p0 + p1);
          mreg[rb][cc]  = mnew;
          av[rb][cc]    = alpha;
          int row = rb*16 + quad*4 + cc;
          Ptl[row*PS + w*16 + l16] = (f16)(w == 0 ? p0 : p1);
          if (w == 0 && l16 == 0) alphas[row] = alpha;
        }
      }
    }
    __syncthreads();

    if (w >= 2){
      #pragma unroll
      for (int r2 = 0; r2 < 2; ++r2)
        #pragma unroll
        for (int cc = 0; cc < 4; ++cc)
          av[r2][cc] = alphas[r2*16 + quad*4 + cc];
    }
    {
      bool ne = false;
      #pragma unroll
      for (int r2 = 0; r2 < 2; ++r2)
        #pragma unroll
        for (int cc = 0; cc < 4; ++cc)
          ne |= (av[r2][cc] != 1.0f);
      if (__ballot(ne) != 0ull){
        #pragma unroll
        for (int r2 = 0; r2 < 2; ++r2)
          #pragma unroll
          for (int t = 0; t < 8; ++t)
            #pragma unroll
            for (int cc = 0; cc < 4; ++cc)
              o[r2][t][cc] *= av[r2][cc];
      }
    }
    {
      f16x8 ap0 = *(const f16x8*)(Ptl + (0*16 + l16)*PS + quad*8);
      f16x8 ap1 = *(const f16x8*)(Ptl + (1*16 + l16)*PS + quad*8);
      #pragma unroll
      for (int t = 0; t < 8; ++t){
        int vrow = w*128 + t*16 + l16;
        int pq   = (quad ^ ((t >> 1) & 3)) * 8;
        f16x8 bv = *(const f16x8*)(Vt + (size_t)vrow*VTS3 + pq);
        o[0][t] = __builtin_amdgcn_mfma_f32_16x16x32_f16(ap0, bv, o[0][t], 0,0,0);
        o[1][t] = __builtin_amdgcn_mfma_f32_16x16x32_f16(ap1, bv, o[1][t], 0,0,0);
      }
    }
    __syncthreads();
  }

  if (w == 0 && l16 == 0){
    #pragma unroll
    for (int rb = 0; rb < 2; ++rb)
      #pragma unroll
      for (int cc = 0; cc < 4; ++cc)
        linv_s[rb*16 + quad*4 + cc] = 1.0f / lpart[rb][cc];
  }
  __syncthreads();

  float linv[2][4];
  #pragma unroll
  for (int r2 = 0; r2 < 2; ++r2)
    #pragma unroll
    for (int cc = 0; cc < 4; ++cc)
      linv[r2][cc] = linv_s[r2*16 + quad*4 + cc];

  float* outp = Og + ((size_t)b*SQ + q0)*DD;
  #pragma unroll
  for (int r2 = 0; r2 < 2; ++r2)
    #pragma unroll
    for (int t = 0; t < 8; ++t)
      #pragma unroll
      for (int cc = 0; cc < 4; ++cc){
        int row = r2*16 + quad*4 + cc;
        int col = w*128 + t*16 + l16;
        outp[(size_t)row*DD + col] = o[r2][t][cc] * linv[r2][cc];
      }
}

// =================== launch ===================

extern "C" void kernel_launch(void* const* d_in, const int* in_sizes, int n_in,
                              void* d_out, int out_size, void* d_ws, size_t ws_size,
                              hipStream_t stream)
{
  const float* Qg = (const float*)d_in[0];
  const float* Vg = (const float*)d_in[1];
  float* Og = (float*)d_out;

  const size_t PB  = (size_t)NB*SQ*SK*2;   // 32 MiB (P)
  const size_t VTB = (size_t)NB*DD*SK*2;   // 16 MiB (VTt)

  if (ws_size >= PB && d_ws != nullptr){
    unsigned short* P = (unsigned short*)d_ws;
    f16* Q16 = (f16*)d_out;                    // d_out hosts Q16+V16 until gemm_o
    f16* V16 = Q16 + (size_t)NB*SQ*DD;
    const bool tier1 = (ws_size >= PB + VTB);

    (void)hipFuncSetAttribute(reinterpret_cast<const void*>(gemm_s),
                              hipFuncAttributeMaxDynamicSharedMemorySize, 131072);
    if (tier1){
      unsigned short* VTt = (unsigned short*)((char*)d_ws + PB);
      (void)hipFuncSetAttribute(reinterpret_cast<const void*>(gemm_o),
                                hipFuncAttributeMaxDynamicSharedMemorySize, 65536);
      prep_all<<<dim3(6144), dim3(256), 0, stream>>>(Qg, Vg, Q16, V16, VTt);
      gemm_s<<<dim3(256), dim3(512), 131072, stream>>>(Q16, V16, P);
      gemm_o<<<dim3(512),  dim3(256), 65536, stream>>>(P, VTt, Og);
    } else {
      (void)hipFuncSetAttribute(reinterpret_cast<const void*>(gemm_pv),
                                hipFuncAttributeMaxDynamicSharedMemorySize, 68096);
      cvt_f16<<<dim3(4096), dim3(256), 0, stream>>>(Qg, Q16);
      cvt_f16<<<dim3(4096), dim3(256), 0, stream>>>(Vg, V16);
      gemm_s<<<dim3(256), dim3(512), 131072, stream>>>(Q16, V16, P);
      gemm_pv<<<dim3(512), dim3(512), 68096, stream>>>(Vg, P, Og);
    }
  } else {
    size_t smem = (size_t)BN*VS*sizeof(f16)
                + (size_t)DD*VTS3*sizeof(f16)
                + (size_t)BM*PS*sizeof(f16)
                + (size_t)(2*8*64*4)*sizeof(float)
                + (size_t)(BM + BM)*sizeof(float);
    (void)hipFuncSetAttribute(reinterpret_cast<const void*>(luong_attn_r3),
                              hipFuncAttributeMaxDynamicSharedMemorySize, (int)smem);
    luong_attn_r3<<<dim3(NB*(SQ/BM)), dim3(512), smem, stream>>>(Qg, Vg, Og);
  }
}